// Round 2
// baseline (2682.486 us; speedup 1.0000x reference)
//
#include <hip/hip_runtime.h>
#include <math.h>

#define NV 204800
#define NE 409600
#define NG 512
#define V_PER 400
#define E_PER 800

#define BE 128   // edges (or vertices) per block
#define KT 32    // k-tile

// ---------------- Kernel 1: vertex MLP  fv = sigmoid(relu(x@W1+b1)@W2+b2) ---
// Register-tiled: per-thread 4 (vertices) x 8 (hidden j) accumulator tile.
__global__ __launch_bounds__(256, 3)
void k_vertex_mlp(const float* __restrict__ x, const float* __restrict__ W1,
                  const float* __restrict__ b1, const float* __restrict__ W2,
                  const float* __restrict__ b2, float* __restrict__ fv) {
  // union region: phase1 = Wt[2][32][64] (16KB) + xt[2][32][128] (32KB) = 48KB
  //               phase2 = hs[128][65] (33.3KB)
  __shared__ __align__(16) char smem[49152];
  float (*Wt)[KT][64] = (float (*)[KT][64])smem;
  float (*xt)[KT][BE] = (float (*)[KT][BE])(smem + 2 * KT * 64 * 4);
  float (*hs)[65] = (float (*)[65])smem;
  __shared__ float W2s[64 * 8];

  const int tid = threadIdx.x;
  const long vb = (long)blockIdx.x * BE;

  if (tid < 128) ((float4*)W2s)[tid] = ((const float4*)W2)[tid];

  const int v = tid >> 1, h = tid & 1;         // staging: 2 threads per vertex row
  const int jg = tid & 7, eg = tid >> 3;       // compute: j0=jg*8, v0=eg*4

  float4 pa[4];  // prefetch regs (16 floats of one half-row)
  float4 wA, wB;

  // bias + layer-2 params into regs
  const float4 bb0 = *(const float4*)(b1 + jg * 8);
  const float4 bb1 = *(const float4*)(b1 + jg * 8 + 4);

  float acc[4][8];
  #pragma unroll
  for (int i = 0; i < 4; ++i) {
    acc[i][0] = bb0.x; acc[i][1] = bb0.y; acc[i][2] = bb0.z; acc[i][3] = bb0.w;
    acc[i][4] = bb1.x; acc[i][5] = bb1.y; acc[i][6] = bb1.z; acc[i][7] = bb1.w;
  }

  // ---- stage tile 0
  {
    const float4* src = (const float4*)(x + (vb + v) * 128 + h * 16);
    #pragma unroll
    for (int i = 0; i < 4; ++i) pa[i] = src[i];
    wA = ((const float4*)W1)[tid];
    wB = ((const float4*)W1)[tid + 256];
    #pragma unroll
    for (int i = 0; i < 4; ++i) {
      xt[0][h * 16 + i * 4 + 0][v] = pa[i].x;
      xt[0][h * 16 + i * 4 + 1][v] = pa[i].y;
      xt[0][h * 16 + i * 4 + 2][v] = pa[i].z;
      xt[0][h * 16 + i * 4 + 3][v] = pa[i].w;
    }
    ((float4*)&Wt[0][0][0])[tid] = wA;
    ((float4*)&Wt[0][0][0])[tid + 256] = wB;
  }
  __syncthreads();

  int buf = 0;
  for (int t = 0; t < 4; ++t) {
    if (t < 3) {  // issue next-tile global loads (latency hides under FMAs)
      const float4* src = (const float4*)(x + (vb + v) * 128 + (t + 1) * KT + h * 16);
      #pragma unroll
      for (int i = 0; i < 4; ++i) pa[i] = src[i];
      wA = ((const float4*)(W1 + (t + 1) * KT * 64))[tid];
      wB = ((const float4*)(W1 + (t + 1) * KT * 64))[tid + 256];
    }
    #pragma unroll
    for (int kk = 0; kk < KT; ++kk) {
      const float4 av = *(const float4*)&xt[buf][kk][eg * 4];
      const float4 w0 = *(const float4*)&Wt[buf][kk][jg * 8];
      const float4 w1 = *(const float4*)&Wt[buf][kk][jg * 8 + 4];
      const float a[4] = {av.x, av.y, av.z, av.w};
      const float w[8] = {w0.x, w0.y, w0.z, w0.w, w1.x, w1.y, w1.z, w1.w};
      #pragma unroll
      for (int i = 0; i < 4; ++i)
        #pragma unroll
        for (int jj = 0; jj < 8; ++jj) acc[i][jj] = fmaf(a[i], w[jj], acc[i][jj]);
    }
    if (t < 3) {
      #pragma unroll
      for (int i = 0; i < 4; ++i) {
        xt[buf ^ 1][h * 16 + i * 4 + 0][v] = pa[i].x;
        xt[buf ^ 1][h * 16 + i * 4 + 1][v] = pa[i].y;
        xt[buf ^ 1][h * 16 + i * 4 + 2][v] = pa[i].z;
        xt[buf ^ 1][h * 16 + i * 4 + 3][v] = pa[i].w;
      }
      ((float4*)&Wt[buf ^ 1][0][0])[tid] = wA;
      ((float4*)&Wt[buf ^ 1][0][0])[tid + 256] = wB;
      __syncthreads();
      buf ^= 1;
    }
  }
  __syncthreads();  // before reusing union region as hs

  #pragma unroll
  for (int i = 0; i < 4; ++i) {
    float4 r0 = make_float4(fmaxf(acc[i][0], 0.f), fmaxf(acc[i][1], 0.f),
                            fmaxf(acc[i][2], 0.f), fmaxf(acc[i][3], 0.f));
    float4 r1 = make_float4(fmaxf(acc[i][4], 0.f), fmaxf(acc[i][5], 0.f),
                            fmaxf(acc[i][6], 0.f), fmaxf(acc[i][7], 0.f));
    *(float4*)&hs[eg * 4 + i][jg * 8] = r0;
    *(float4*)&hs[eg * 4 + i][jg * 8 + 4] = r1;
  }
  __syncthreads();

  // layer 2 + sigmoid: 4 passes of 32 rows
  const int o = tid & 7;
  const float bb2 = b2[o];
  #pragma unroll
  for (int p = 0; p < 4; ++p) {
    const int e2 = p * 32 + (tid >> 3);
    float a2 = bb2;
    #pragma unroll 8
    for (int jj = 0; jj < 64; ++jj) a2 = fmaf(hs[e2][jj], W2s[jj * 8 + o], a2);
    fv[(vb + e2) * 8 + o] = 1.0f / (1.0f + __expf(-a2));
  }
}

// ---------------- Kernel 2: edge MLP  fe = sigmoid(relu(xe@We1+be1)@We2+be2) -
__global__ __launch_bounds__(256, 3)
void k_edge_mlp(const float* __restrict__ x, const float* __restrict__ pos,
                const int* __restrict__ srcp, const int* __restrict__ dstp,
                const float* __restrict__ We1, const float* __restrict__ be1,
                const float* __restrict__ We2, const float* __restrict__ be2,
                float* __restrict__ fe) {
  __shared__ __align__(16) char smem[49152];
  float (*Wt)[KT][64] = (float (*)[KT][64])smem;
  float (*xt)[KT][BE] = (float (*)[KT][BE])(smem + 2 * KT * 64 * 4);
  float (*hs)[65] = (float (*)[65])smem;
  __shared__ float W2s[64 * 8];
  __shared__ float ds[BE];

  const int tid = threadIdx.x;
  // XCD-chunked swizzle: 3200 blocks = 8 x 400; keep a graph's ~6 blocks on one XCD
  const int bid = blockIdx.x;
  const int lb = (bid & 7) * (NE / BE / 8) + (bid >> 3);
  const int eb = lb * BE;

  if (tid < 128) ((float4*)W2s)[tid] = ((const float4*)We2)[tid];

  const int e = tid >> 1, h = tid & 1;
  const int jg = tid & 7, eg = tid >> 3;
  const int s = srcp[eb + e], d = dstp[eb + e];

  float4 pa[4], pb[4];
  float4 wA, wB;

  const float4 bb0 = *(const float4*)(be1 + jg * 8);
  const float4 bb1 = *(const float4*)(be1 + jg * 8 + 4);
  // dist-column weights (We1 row 128)
  const float4 wd0 = *(const float4*)(We1 + 128 * 64 + jg * 8);
  const float4 wd1 = *(const float4*)(We1 + 128 * 64 + jg * 8 + 4);

  float acc[4][8];
  #pragma unroll
  for (int i = 0; i < 4; ++i) {
    acc[i][0] = bb0.x; acc[i][1] = bb0.y; acc[i][2] = bb0.z; acc[i][3] = bb0.w;
    acc[i][4] = bb1.x; acc[i][5] = bb1.y; acc[i][6] = bb1.z; acc[i][7] = bb1.w;
  }

  // distance per edge
  if (tid < BE) {
    const int s2 = srcp[eb + tid], d2 = dstp[eb + tid];
    const float dx = pos[s2 * 3 + 0] - pos[d2 * 3 + 0];
    const float dy = pos[s2 * 3 + 1] - pos[d2 * 3 + 1];
    const float dz = pos[s2 * 3 + 2] - pos[d2 * 3 + 2];
    ds[tid] = sqrtf(dx * dx + dy * dy + dz * dz);
  }

  // ---- stage tile 0
  {
    const float4* ps = (const float4*)(x + (long)s * 128 + h * 16);
    const float4* pd = (const float4*)(x + (long)d * 128 + h * 16);
    #pragma unroll
    for (int i = 0; i < 4; ++i) { pa[i] = ps[i]; pb[i] = pd[i]; }
    wA = ((const float4*)We1)[tid];
    wB = ((const float4*)We1)[tid + 256];
    #pragma unroll
    for (int i = 0; i < 4; ++i) {
      xt[0][h * 16 + i * 4 + 0][e] = pa[i].x + pb[i].x;
      xt[0][h * 16 + i * 4 + 1][e] = pa[i].y + pb[i].y;
      xt[0][h * 16 + i * 4 + 2][e] = pa[i].z + pb[i].z;
      xt[0][h * 16 + i * 4 + 3][e] = pa[i].w + pb[i].w;
    }
    ((float4*)&Wt[0][0][0])[tid] = wA;
    ((float4*)&Wt[0][0][0])[tid + 256] = wB;
  }
  __syncthreads();

  int buf = 0;
  for (int t = 0; t < 4; ++t) {
    if (t < 3) {
      const float4* ps = (const float4*)(x + (long)s * 128 + (t + 1) * KT + h * 16);
      const float4* pd = (const float4*)(x + (long)d * 128 + (t + 1) * KT + h * 16);
      #pragma unroll
      for (int i = 0; i < 4; ++i) { pa[i] = ps[i]; pb[i] = pd[i]; }
      wA = ((const float4*)(We1 + (t + 1) * KT * 64))[tid];
      wB = ((const float4*)(We1 + (t + 1) * KT * 64))[tid + 256];
    }
    #pragma unroll
    for (int kk = 0; kk < KT; ++kk) {
      const float4 av = *(const float4*)&xt[buf][kk][eg * 4];
      const float4 w0 = *(const float4*)&Wt[buf][kk][jg * 8];
      const float4 w1 = *(const float4*)&Wt[buf][kk][jg * 8 + 4];
      const float a[4] = {av.x, av.y, av.z, av.w};
      const float w[8] = {w0.x, w0.y, w0.z, w0.w, w1.x, w1.y, w1.z, w1.w};
      #pragma unroll
      for (int i = 0; i < 4; ++i)
        #pragma unroll
        for (int jj = 0; jj < 8; ++jj) acc[i][jj] = fmaf(a[i], w[jj], acc[i][jj]);
    }
    if (t < 3) {
      #pragma unroll
      for (int i = 0; i < 4; ++i) {
        xt[buf ^ 1][h * 16 + i * 4 + 0][e] = pa[i].x + pb[i].x;
        xt[buf ^ 1][h * 16 + i * 4 + 1][e] = pa[i].y + pb[i].y;
        xt[buf ^ 1][h * 16 + i * 4 + 2][e] = pa[i].z + pb[i].z;
        xt[buf ^ 1][h * 16 + i * 4 + 3][e] = pa[i].w + pb[i].w;
      }
      ((float4*)&Wt[buf ^ 1][0][0])[tid] = wA;
      ((float4*)&Wt[buf ^ 1][0][0])[tid + 256] = wB;
      __syncthreads();
      buf ^= 1;
    }
  }

  // dist term (k = 128)
  {
    const float wdl[8] = {wd0.x, wd0.y, wd0.z, wd0.w, wd1.x, wd1.y, wd1.z, wd1.w};
    #pragma unroll
    for (int i = 0; i < 4; ++i) {
      const float dv = ds[eg * 4 + i];
      #pragma unroll
      for (int jj = 0; jj < 8; ++jj) acc[i][jj] = fmaf(dv, wdl[jj], acc[i][jj]);
    }
  }
  __syncthreads();  // before union reuse

  #pragma unroll
  for (int i = 0; i < 4; ++i) {
    float4 r0 = make_float4(fmaxf(acc[i][0], 0.f), fmaxf(acc[i][1], 0.f),
                            fmaxf(acc[i][2], 0.f), fmaxf(acc[i][3], 0.f));
    float4 r1 = make_float4(fmaxf(acc[i][4], 0.f), fmaxf(acc[i][5], 0.f),
                            fmaxf(acc[i][6], 0.f), fmaxf(acc[i][7], 0.f));
    *(float4*)&hs[eg * 4 + i][jg * 8] = r0;
    *(float4*)&hs[eg * 4 + i][jg * 8 + 4] = r1;
  }
  __syncthreads();

  const int o = tid & 7;
  const float bb2 = be2[o];
  #pragma unroll
  for (int p = 0; p < 4; ++p) {
    const int e2 = p * 32 + (tid >> 3);
    float a2 = bb2;
    #pragma unroll 8
    for (int jj = 0; jj < 64; ++jj) a2 = fmaf(hs[e2][jj], W2s[jj * 8 + o], a2);
    fe[(long)(eb + e2) * 8 + o] = 1.0f / (1.0f + __expf(-a2));
  }
}

// ------- Kernel 3: per-graph LDS scatter min/max + reduce + lin0 -> h -------
// LDS planes are [f][400] so atomic lanes (random v, fixed f) spread over banks.
__global__ __launch_bounds__(256, 2)
void k_graph_reduce(const float* __restrict__ fv, const float* __restrict__ fe,
                    const int* __restrict__ srcp, const int* __restrict__ dstp,
                    const float* __restrict__ Wd0, const float* __restrict__ bd0,
                    const float* __restrict__ Wd1, const float* __restrict__ bd1,
                    float* __restrict__ hbuf) {
  __shared__ unsigned dminS[8 * V_PER];  // 12.8 KB, plane f at f*V_PER
  __shared__ unsigned dmaxS[8 * V_PER];  // 12.8 KB
  __shared__ float red[256];
  __shared__ float sums[3][8];
  const int tid = threadIdx.x;
  const int g = blockIdx.x;

  for (int i = tid; i < 8 * V_PER; i += 256) {
    dminS[i] = 0x7F800000u;  // +inf bits (fe > 0 so uint compare == float compare)
    dmaxS[i] = 0u;           // 0.0f bits
  }
  __syncthreads();

  const int eb = g * E_PER;
  const int vb = g * V_PER;
  for (int e = tid; e < E_PER; e += 256) {
    const int ls = srcp[eb + e] - vb;
    const int ld = dstp[eb + e] - vb;
    const uint4 f0 = ((const uint4*)(fe + (long)(eb + e) * 8))[0];
    const uint4 f1 = ((const uint4*)(fe + (long)(eb + e) * 8))[1];
    const unsigned fb[8] = {f0.x, f0.y, f0.z, f0.w, f1.x, f1.y, f1.z, f1.w};
    #pragma unroll
    for (int f = 0; f < 8; ++f) {
      atomicMin(&dminS[f * V_PER + ls], fb[f]);
      atomicMax(&dmaxS[f * V_PER + ls], fb[f]);
      atomicMin(&dminS[f * V_PER + ld], fb[f]);
      atomicMax(&dmaxS[f * V_PER + ld], fb[f]);
    }
  }
  __syncthreads();

  const int f = tid & 7;
  float sfv = 0.f, smin = 0.f, smax = 0.f;
  for (int v = tid >> 3; v < V_PER; v += 32) {
    sfv += fv[(long)(vb + v) * 8 + f];
    const unsigned mn = dminS[f * V_PER + v];
    if (mn == 0x7F800000u) { smin += 1.0f; smax += 1.0f; }
    else { smin += __uint_as_float(mn); smax += __uint_as_float(dmaxS[f * V_PER + v]); }
  }
  red[tid] = sfv; __syncthreads();
  for (int s = 128; s >= 8; s >>= 1) { if (tid < s) red[tid] += red[tid + s]; __syncthreads(); }
  if (tid < 8) sums[0][tid] = red[tid];
  __syncthreads();
  red[tid] = smax; __syncthreads();
  for (int s = 128; s >= 8; s >>= 1) { if (tid < s) red[tid] += red[tid + s]; __syncthreads(); }
  if (tid < 8) sums[1][tid] = red[tid];
  __syncthreads();
  red[tid] = smin; __syncthreads();
  for (int s = 128; s >= 8; s >>= 1) { if (tid < s) red[tid] += red[tid + s]; __syncthreads(); }
  if (tid < 8) sums[2][tid] = red[tid];
  __syncthreads();

  if (tid < 64) {
    const int o = tid;
    const float inv = 1.0f / (float)V_PER;
    float acc = bd0[o];
    #pragma unroll
    for (int ff = 0; ff < 8; ++ff) {
      acc = fmaf(sums[0][ff] * inv, Wd0[(4 * ff + 1) * 64 + o], acc);
      acc = fmaf(sums[1][ff] * inv, Wd0[(4 * ff + 2) * 64 + o], acc);
      acc = fmaf(sums[2][ff] * inv, Wd0[(4 * ff + 3) * 64 + o], acc);
    }
    const float x1 = Wd1[64 + o] + Wd1[128 + o] + Wd1[192 + o] + bd1[o];
    hbuf[g * 64 + o] = acc + x1;
  }
}

// ---------------- Kernel 4: BatchNorm stats over 512 graphs -----------------
__global__ __launch_bounds__(256)
void k_bn_stats(const float* __restrict__ hbuf, float* __restrict__ mu,
                float* __restrict__ rstd) {
  __shared__ float rs[256], rs2[256];
  const int tid = threadIdx.x;
  const int c = tid & 63, rg = tid >> 6;
  float s = 0.f, s2 = 0.f;
  for (int r = rg * 128; r < rg * 128 + 128; ++r) {
    const float v = hbuf[r * 64 + c];
    s += v; s2 += v * v;
  }
  rs[tid] = s; rs2[tid] = s2; __syncthreads();
  if (tid < 128) { rs[tid] += rs[tid + 128]; rs2[tid] += rs2[tid + 128]; }
  __syncthreads();
  if (tid < 64) {
    const float st = rs[tid] + rs[tid + 64];
    const float st2 = rs2[tid] + rs2[tid + 64];
    const float m = st / 512.0f;
    const float var = st2 / 512.0f - m * m;
    mu[tid] = m;
    rstd[tid] = rsqrtf(var + 1e-5f);
  }
}

// ---------------- Kernel 5: BN apply + out MLP ------------------------------
__global__ __launch_bounds__(256)
void k_out_mlp(const float* __restrict__ hbuf, const float* __restrict__ mu,
               const float* __restrict__ rstd, const float* __restrict__ gam,
               const float* __restrict__ bet, const float* __restrict__ Wo1,
               const float* __restrict__ bo1, const float* __restrict__ Wo2,
               const float* __restrict__ bo2, float* __restrict__ out) {
  __shared__ float W1s[64 * 64], W2s[64 * 64];
  __shared__ float hn[4][64], t1[4][64];
  __shared__ float mus[64], rstds[64], gs[64], bs[64], b1s[64], b2s[64];
  const int tid = threadIdx.x;
  for (int i = tid; i < 4096; i += 256) { W1s[i] = Wo1[i]; W2s[i] = Wo2[i]; }
  if (tid < 64) {
    mus[tid] = mu[tid]; rstds[tid] = rstd[tid]; gs[tid] = gam[tid];
    bs[tid] = bet[tid]; b1s[tid] = bo1[tid]; b2s[tid] = bo2[tid];
  }
  __syncthreads();
  const int r = tid >> 6, o = tid & 63;
  for (int it = 0; it < 4; ++it) {
    const int row = blockIdx.x * 16 + it * 4 + r;
    hn[r][o] = (hbuf[row * 64 + o] - mus[o]) * rstds[o] * gs[o] + bs[o];
    __syncthreads();
    float a = b1s[o];
    #pragma unroll 8
    for (int i = 0; i < 64; ++i) a = fmaf(hn[r][i], W1s[i * 64 + o], a);
    t1[r][o] = fmaxf(a, 0.f);
    __syncthreads();
    float a2 = b2s[o];
    #pragma unroll 8
    for (int i = 0; i < 64; ++i) a2 = fmaf(t1[r][i], W2s[i * 64 + o], a2);
    out[row * 64 + o] = a2;
    __syncthreads();
  }
}

extern "C" void kernel_launch(void* const* d_in, const int* in_sizes, int n_in,
                              void* d_out, int out_size, void* d_ws, size_t ws_size,
                              hipStream_t stream) {
  const float* x   = (const float*)d_in[0];
  const float* pos = (const float*)d_in[1];
  const int*   ei  = (const int*)d_in[2];
  const float* W1  = (const float*)d_in[6];
  const float* b1  = (const float*)d_in[7];
  const float* W2  = (const float*)d_in[8];
  const float* b2  = (const float*)d_in[9];
  const float* We1 = (const float*)d_in[10];
  const float* be1 = (const float*)d_in[11];
  const float* We2 = (const float*)d_in[12];
  const float* be2 = (const float*)d_in[13];
  const float* Wd0 = (const float*)d_in[14];
  const float* bd0 = (const float*)d_in[15];
  const float* Wd1 = (const float*)d_in[16];
  const float* bd1 = (const float*)d_in[17];
  const float* gam = (const float*)d_in[18];
  const float* bet = (const float*)d_in[19];
  const float* Wo1 = (const float*)d_in[20];
  const float* bo1 = (const float*)d_in[21];
  const float* Wo2 = (const float*)d_in[22];
  const float* bo2 = (const float*)d_in[23];

  const int* srcp = ei;
  const int* dstp = ei + NE;

  float* fv   = (float*)d_ws;                  // NV*8
  float* fe   = fv + (size_t)NV * 8;           // NE*8
  float* hb   = fe + (size_t)NE * 8;           // NG*64
  float* mu   = hb + NG * 64;                  // 64
  float* rstd = mu + 64;                       // 64

  hipLaunchKernelGGL(k_vertex_mlp, dim3(NV / BE), dim3(256), 0, stream,
                     x, W1, b1, W2, b2, fv);
  hipLaunchKernelGGL(k_edge_mlp, dim3(NE / BE), dim3(256), 0, stream,
                     x, pos, srcp, dstp, We1, be1, We2, be2, fe);
  hipLaunchKernelGGL(k_graph_reduce, dim3(NG), dim3(256), 0, stream,
                     fv, fe, srcp, dstp, Wd0, bd0, Wd1, bd1, hb);
  hipLaunchKernelGGL(k_bn_stats, dim3(1), dim3(256), 0, stream, hb, mu, rstd);
  hipLaunchKernelGGL(k_out_mlp, dim3(NG / 16), dim3(256), 0, stream,
                     hb, mu, rstd, gam, bet, Wo1, bo1, Wo2, bo2, (float*)d_out);
}

// Round 3
// 403.205 us; speedup vs baseline: 6.6529x; 6.6529x over previous
//
#include <hip/hip_runtime.h>
#include <math.h>

#define NV 204800
#define NE 409600
#define NG 512
#define V_PER 400
#define E_PER 800

#define BE 128   // rows (vertices/edges) per block
#define KT 32    // k-tile

// ---------------- Kernel 1: vertex MLP  fv = sigmoid(relu(x@W1+b1)@W2+b2) ---
// Register-tiled: per-thread 4 rows x 8 hidden-j accumulators. Single-buffered
// LDS staging (no reg prefetch -- R2's spilled); layer 2 via shfl butterfly.
__global__ __launch_bounds__(256)
void k_vertex_mlp(const float* __restrict__ x, const float* __restrict__ W1,
                  const float* __restrict__ b1, const float* __restrict__ W2,
                  const float* __restrict__ b2, float* __restrict__ fv) {
  __shared__ float Wt[KT][64];     // 8 KB   [k][j]
  __shared__ float xt[KT][BE];     // 16 KB  [k][row]
  __shared__ float W2s[64 * 8];    // 2 KB

  const int tid = threadIdx.x;
  const long vb = (long)blockIdx.x * BE;

  if (tid < 128) ((float4*)W2s)[tid] = ((const float4*)W2)[tid];

  const int v = tid >> 1, h = tid & 1;     // staging: 2 threads per row
  const int jg = tid & 7, eg = tid >> 3;   // compute: j0=jg*8, row0=eg*4

  const float4 bb0 = *(const float4*)(b1 + jg * 8);
  const float4 bb1 = *(const float4*)(b1 + jg * 8 + 4);
  const float4 b2a = *(const float4*)b2;
  const float4 b2b = *(const float4*)(b2 + 4);

  float acc[4][8];
  #pragma unroll
  for (int i = 0; i < 4; ++i) {
    acc[i][0] = bb0.x; acc[i][1] = bb0.y; acc[i][2] = bb0.z; acc[i][3] = bb0.w;
    acc[i][4] = bb1.x; acc[i][5] = bb1.y; acc[i][6] = bb1.z; acc[i][7] = bb1.w;
  }

  #pragma unroll 1
  for (int t = 0; t < 4; ++t) {
    { // stage tile t: x rows -> transposed xt, W1 slab -> Wt
      const float4* src = (const float4*)(x + (vb + v) * 128 + t * KT + h * 16);
      const float4 a0 = src[0], a1 = src[1], a2 = src[2], a3 = src[3];
      const float4 wA = ((const float4*)(W1 + t * KT * 64))[tid];
      const float4 wB = ((const float4*)(W1 + t * KT * 64))[tid + 256];
      const int r = h * 16;
      xt[r + 0][v] = a0.x; xt[r + 1][v] = a0.y; xt[r + 2][v] = a0.z; xt[r + 3][v] = a0.w;
      xt[r + 4][v] = a1.x; xt[r + 5][v] = a1.y; xt[r + 6][v] = a1.z; xt[r + 7][v] = a1.w;
      xt[r + 8][v] = a2.x; xt[r + 9][v] = a2.y; xt[r +10][v] = a2.z; xt[r +11][v] = a2.w;
      xt[r +12][v] = a3.x; xt[r +13][v] = a3.y; xt[r +14][v] = a3.z; xt[r +15][v] = a3.w;
      ((float4*)&Wt[0][0])[tid] = wA;
      ((float4*)&Wt[0][0])[tid + 256] = wB;
    }
    __syncthreads();
    #pragma unroll
    for (int kk = 0; kk < KT; ++kk) {
      const float4 av = *(const float4*)&xt[kk][eg * 4];
      const float4 w0 = *(const float4*)&Wt[kk][jg * 8];
      const float4 w1 = *(const float4*)&Wt[kk][jg * 8 + 4];
      const float a[4] = {av.x, av.y, av.z, av.w};
      const float w[8] = {w0.x, w0.y, w0.z, w0.w, w1.x, w1.y, w1.z, w1.w};
      #pragma unroll
      for (int i = 0; i < 4; ++i)
        #pragma unroll
        for (int jj = 0; jj < 8; ++jj) acc[i][jj] = fmaf(a[i], w[jj], acc[i][jj]);
    }
    __syncthreads();
  }

  // layer 2: per-thread partials over my 8 j's, butterfly over jg group
  float p[4][8];
  #pragma unroll
  for (int i = 0; i < 4; ++i)
    #pragma unroll
    for (int o = 0; o < 8; ++o) p[i][o] = 0.f;
  #pragma unroll
  for (int jj = 0; jj < 8; ++jj) {
    const float4 w20 = *(const float4*)&W2s[(jg * 8 + jj) * 8];
    const float4 w21 = *(const float4*)&W2s[(jg * 8 + jj) * 8 + 4];
    const float w2r[8] = {w20.x, w20.y, w20.z, w20.w, w21.x, w21.y, w21.z, w21.w};
    #pragma unroll
    for (int i = 0; i < 4; ++i) {
      const float hv = fmaxf(acc[i][jj], 0.f);
      #pragma unroll
      for (int o = 0; o < 8; ++o) p[i][o] = fmaf(hv, w2r[o], p[i][o]);
    }
  }
  #pragma unroll
  for (int m = 1; m <= 4; m <<= 1)
    #pragma unroll
    for (int i = 0; i < 4; ++i)
      #pragma unroll
      for (int o = 0; o < 8; ++o) p[i][o] += __shfl_xor(p[i][o], m, 64);

  if (jg < 4) {
    const long e2 = vb + eg * 4 + jg;
    const float b2r[8] = {b2a.x, b2a.y, b2a.z, b2a.w, b2b.x, b2b.y, b2b.z, b2b.w};
    float vout[8];
    #pragma unroll
    for (int o = 0; o < 8; ++o) vout[o] = 1.0f / (1.0f + __expf(-(p[jg][o] + b2r[o])));
    *(float4*)&fv[e2 * 8]     = make_float4(vout[0], vout[1], vout[2], vout[3]);
    *(float4*)&fv[e2 * 8 + 4] = make_float4(vout[4], vout[5], vout[6], vout[7]);
  }
}

// ---------------- Kernel 2: edge MLP  fe = sigmoid(relu(xe@We1+be1)@We2+be2) -
__global__ __launch_bounds__(256)
void k_edge_mlp(const float* __restrict__ x, const float* __restrict__ pos,
                const int* __restrict__ srcp, const int* __restrict__ dstp,
                const float* __restrict__ We1, const float* __restrict__ be1,
                const float* __restrict__ We2, const float* __restrict__ be2,
                float* __restrict__ fe) {
  __shared__ float Wt[KT][64];
  __shared__ float xt[KT][BE];
  __shared__ float W2s[64 * 8];
  __shared__ float ds[BE];

  const int tid = threadIdx.x;
  // XCD-chunked swizzle: 3200 blocks = 8 XCDs x 400; graph locality per XCD
  const int bid = blockIdx.x;
  const int lb = (bid & 7) * (NE / BE / 8) + (bid >> 3);
  const long eb = (long)lb * BE;

  if (tid < 128) ((float4*)W2s)[tid] = ((const float4*)We2)[tid];

  const int e = tid >> 1, h = tid & 1;
  const int jg = tid & 7, eg = tid >> 3;
  const int s = srcp[eb + e], d = dstp[eb + e];

  const float4 bb0 = *(const float4*)(be1 + jg * 8);
  const float4 bb1 = *(const float4*)(be1 + jg * 8 + 4);
  const float4 wd0 = *(const float4*)(We1 + 128 * 64 + jg * 8);
  const float4 wd1 = *(const float4*)(We1 + 128 * 64 + jg * 8 + 4);
  const float4 b2a = *(const float4*)be2;
  const float4 b2b = *(const float4*)(be2 + 4);

  float acc[4][8];
  #pragma unroll
  for (int i = 0; i < 4; ++i) {
    acc[i][0] = bb0.x; acc[i][1] = bb0.y; acc[i][2] = bb0.z; acc[i][3] = bb0.w;
    acc[i][4] = bb1.x; acc[i][5] = bb1.y; acc[i][6] = bb1.z; acc[i][7] = bb1.w;
  }

  if (tid < BE) { // distance per edge
    const int s2 = srcp[eb + tid], d2 = dstp[eb + tid];
    const float dx = pos[s2 * 3 + 0] - pos[d2 * 3 + 0];
    const float dy = pos[s2 * 3 + 1] - pos[d2 * 3 + 1];
    const float dz = pos[s2 * 3 + 2] - pos[d2 * 3 + 2];
    ds[tid] = sqrtf(dx * dx + dy * dy + dz * dz);
  }

  #pragma unroll 1
  for (int t = 0; t < 4; ++t) {
    { // stage: gather x[s]+x[d] slab -> transposed xt; We1 slab -> Wt
      const float4* ps = (const float4*)(x + (long)s * 128 + t * KT + h * 16);
      const float4* pd = (const float4*)(x + (long)d * 128 + t * KT + h * 16);
      const float4 a0 = ps[0], a1 = ps[1], a2 = ps[2], a3 = ps[3];
      const float4 c0 = pd[0], c1 = pd[1], c2 = pd[2], c3 = pd[3];
      const float4 wA = ((const float4*)(We1 + t * KT * 64))[tid];
      const float4 wB = ((const float4*)(We1 + t * KT * 64))[tid + 256];
      const int r = h * 16;
      xt[r + 0][e] = a0.x + c0.x; xt[r + 1][e] = a0.y + c0.y;
      xt[r + 2][e] = a0.z + c0.z; xt[r + 3][e] = a0.w + c0.w;
      xt[r + 4][e] = a1.x + c1.x; xt[r + 5][e] = a1.y + c1.y;
      xt[r + 6][e] = a1.z + c1.z; xt[r + 7][e] = a1.w + c1.w;
      xt[r + 8][e] = a2.x + c2.x; xt[r + 9][e] = a2.y + c2.y;
      xt[r +10][e] = a2.z + c2.z; xt[r +11][e] = a2.w + c2.w;
      xt[r +12][e] = a3.x + c3.x; xt[r +13][e] = a3.y + c3.y;
      xt[r +14][e] = a3.z + c3.z; xt[r +15][e] = a3.w + c3.w;
      ((float4*)&Wt[0][0])[tid] = wA;
      ((float4*)&Wt[0][0])[tid + 256] = wB;
    }
    __syncthreads();
    #pragma unroll
    for (int kk = 0; kk < KT; ++kk) {
      const float4 av = *(const float4*)&xt[kk][eg * 4];
      const float4 w0 = *(const float4*)&Wt[kk][jg * 8];
      const float4 w1 = *(const float4*)&Wt[kk][jg * 8 + 4];
      const float a[4] = {av.x, av.y, av.z, av.w};
      const float w[8] = {w0.x, w0.y, w0.z, w0.w, w1.x, w1.y, w1.z, w1.w};
      #pragma unroll
      for (int i = 0; i < 4; ++i)
        #pragma unroll
        for (int jj = 0; jj < 8; ++jj) acc[i][jj] = fmaf(a[i], w[jj], acc[i][jj]);
    }
    __syncthreads();
  }

  { // dist column (k = 128)
    const float wdl[8] = {wd0.x, wd0.y, wd0.z, wd0.w, wd1.x, wd1.y, wd1.z, wd1.w};
    #pragma unroll
    for (int i = 0; i < 4; ++i) {
      const float dv = ds[eg * 4 + i];
      #pragma unroll
      for (int jj = 0; jj < 8; ++jj) acc[i][jj] = fmaf(dv, wdl[jj], acc[i][jj]);
    }
  }

  // layer 2 + butterfly
  float p[4][8];
  #pragma unroll
  for (int i = 0; i < 4; ++i)
    #pragma unroll
    for (int o = 0; o < 8; ++o) p[i][o] = 0.f;
  #pragma unroll
  for (int jj = 0; jj < 8; ++jj) {
    const float4 w20 = *(const float4*)&W2s[(jg * 8 + jj) * 8];
    const float4 w21 = *(const float4*)&W2s[(jg * 8 + jj) * 8 + 4];
    const float w2r[8] = {w20.x, w20.y, w20.z, w20.w, w21.x, w21.y, w21.z, w21.w};
    #pragma unroll
    for (int i = 0; i < 4; ++i) {
      const float hv = fmaxf(acc[i][jj], 0.f);
      #pragma unroll
      for (int o = 0; o < 8; ++o) p[i][o] = fmaf(hv, w2r[o], p[i][o]);
    }
  }
  #pragma unroll
  for (int m = 1; m <= 4; m <<= 1)
    #pragma unroll
    for (int i = 0; i < 4; ++i)
      #pragma unroll
      for (int o = 0; o < 8; ++o) p[i][o] += __shfl_xor(p[i][o], m, 64);

  if (jg < 4) {
    const long e2 = eb + eg * 4 + jg;
    const float b2r[8] = {b2a.x, b2a.y, b2a.z, b2a.w, b2b.x, b2b.y, b2b.z, b2b.w};
    float vout[8];
    #pragma unroll
    for (int o = 0; o < 8; ++o) vout[o] = 1.0f / (1.0f + __expf(-(p[jg][o] + b2r[o])));
    *(float4*)&fe[e2 * 8]     = make_float4(vout[0], vout[1], vout[2], vout[3]);
    *(float4*)&fe[e2 * 8 + 4] = make_float4(vout[4], vout[5], vout[6], vout[7]);
  }
}

// ------- Kernel 3: per-graph LDS scatter min/max + reduce + lin0 -> h -------
// LDS planes are [f][400] so atomic lanes (random v, fixed f) spread over banks.
__global__ __launch_bounds__(256, 2)
void k_graph_reduce(const float* __restrict__ fv, const float* __restrict__ fe,
                    const int* __restrict__ srcp, const int* __restrict__ dstp,
                    const float* __restrict__ Wd0, const float* __restrict__ bd0,
                    const float* __restrict__ Wd1, const float* __restrict__ bd1,
                    float* __restrict__ hbuf) {
  __shared__ unsigned dminS[8 * V_PER];  // 12.8 KB, plane f at f*V_PER
  __shared__ unsigned dmaxS[8 * V_PER];  // 12.8 KB
  __shared__ float red[256];
  __shared__ float sums[3][8];
  const int tid = threadIdx.x;
  const int g = blockIdx.x;

  for (int i = tid; i < 8 * V_PER; i += 256) {
    dminS[i] = 0x7F800000u;  // +inf bits (fe > 0 so uint compare == float compare)
    dmaxS[i] = 0u;           // 0.0f bits
  }
  __syncthreads();

  const int eb = g * E_PER;
  const int vb = g * V_PER;
  for (int e = tid; e < E_PER; e += 256) {
    const int ls = srcp[eb + e] - vb;
    const int ld = dstp[eb + e] - vb;
    const uint4 f0 = ((const uint4*)(fe + (long)(eb + e) * 8))[0];
    const uint4 f1 = ((const uint4*)(fe + (long)(eb + e) * 8))[1];
    const unsigned fb[8] = {f0.x, f0.y, f0.z, f0.w, f1.x, f1.y, f1.z, f1.w};
    #pragma unroll
    for (int f = 0; f < 8; ++f) {
      atomicMin(&dminS[f * V_PER + ls], fb[f]);
      atomicMax(&dmaxS[f * V_PER + ls], fb[f]);
      atomicMin(&dminS[f * V_PER + ld], fb[f]);
      atomicMax(&dmaxS[f * V_PER + ld], fb[f]);
    }
  }
  __syncthreads();

  const int f = tid & 7;
  float sfv = 0.f, smin = 0.f, smax = 0.f;
  for (int v = tid >> 3; v < V_PER; v += 32) {
    sfv += fv[(long)(vb + v) * 8 + f];
    const unsigned mn = dminS[f * V_PER + v];
    if (mn == 0x7F800000u) { smin += 1.0f; smax += 1.0f; }
    else { smin += __uint_as_float(mn); smax += __uint_as_float(dmaxS[f * V_PER + v]); }
  }
  red[tid] = sfv; __syncthreads();
  for (int s = 128; s >= 8; s >>= 1) { if (tid < s) red[tid] += red[tid + s]; __syncthreads(); }
  if (tid < 8) sums[0][tid] = red[tid];
  __syncthreads();
  red[tid] = smax; __syncthreads();
  for (int s = 128; s >= 8; s >>= 1) { if (tid < s) red[tid] += red[tid + s]; __syncthreads(); }
  if (tid < 8) sums[1][tid] = red[tid];
  __syncthreads();
  red[tid] = smin; __syncthreads();
  for (int s = 128; s >= 8; s >>= 1) { if (tid < s) red[tid] += red[tid + s]; __syncthreads(); }
  if (tid < 8) sums[2][tid] = red[tid];
  __syncthreads();

  if (tid < 64) {
    const int o = tid;
    const float inv = 1.0f / (float)V_PER;
    float acc = bd0[o];
    #pragma unroll
    for (int ff = 0; ff < 8; ++ff) {
      acc = fmaf(sums[0][ff] * inv, Wd0[(4 * ff + 1) * 64 + o], acc);
      acc = fmaf(sums[1][ff] * inv, Wd0[(4 * ff + 2) * 64 + o], acc);
      acc = fmaf(sums[2][ff] * inv, Wd0[(4 * ff + 3) * 64 + o], acc);
    }
    const float x1 = Wd1[64 + o] + Wd1[128 + o] + Wd1[192 + o] + bd1[o];
    hbuf[g * 64 + o] = acc + x1;
  }
}

// ---------------- Kernel 4: BatchNorm stats over 512 graphs -----------------
__global__ __launch_bounds__(256)
void k_bn_stats(const float* __restrict__ hbuf, float* __restrict__ mu,
                float* __restrict__ rstd) {
  __shared__ float rs[256], rs2[256];
  const int tid = threadIdx.x;
  const int c = tid & 63, rg = tid >> 6;
  float s = 0.f, s2 = 0.f;
  for (int r = rg * 128; r < rg * 128 + 128; ++r) {
    const float v = hbuf[r * 64 + c];
    s += v; s2 += v * v;
  }
  rs[tid] = s; rs2[tid] = s2; __syncthreads();
  if (tid < 128) { rs[tid] += rs[tid + 128]; rs2[tid] += rs2[tid + 128]; }
  __syncthreads();
  if (tid < 64) {
    const float st = rs[tid] + rs[tid + 64];
    const float st2 = rs2[tid] + rs2[tid + 64];
    const float m = st / 512.0f;
    const float var = st2 / 512.0f - m * m;
    mu[tid] = m;
    rstd[tid] = rsqrtf(var + 1e-5f);
  }
}

// ---------------- Kernel 5: BN apply + out MLP ------------------------------
__global__ __launch_bounds__(256)
void k_out_mlp(const float* __restrict__ hbuf, const float* __restrict__ mu,
               const float* __restrict__ rstd, const float* __restrict__ gam,
               const float* __restrict__ bet, const float* __restrict__ Wo1,
               const float* __restrict__ bo1, const float* __restrict__ Wo2,
               const float* __restrict__ bo2, float* __restrict__ out) {
  __shared__ float W1s[64 * 64], W2s[64 * 64];
  __shared__ float hn[4][64], t1[4][64];
  __shared__ float mus[64], rstds[64], gs[64], bs[64], b1s[64], b2s[64];
  const int tid = threadIdx.x;
  for (int i = tid; i < 4096; i += 256) { W1s[i] = Wo1[i]; W2s[i] = Wo2[i]; }
  if (tid < 64) {
    mus[tid] = mu[tid]; rstds[tid] = rstd[tid]; gs[tid] = gam[tid];
    bs[tid] = bet[tid]; b1s[tid] = bo1[tid]; b2s[tid] = bo2[tid];
  }
  __syncthreads();
  const int r = tid >> 6, o = tid & 63;
  for (int it = 0; it < 4; ++it) {
    const int row = blockIdx.x * 16 + it * 4 + r;
    hn[r][o] = (hbuf[row * 64 + o] - mus[o]) * rstds[o] * gs[o] + bs[o];
    __syncthreads();
    float a = b1s[o];
    #pragma unroll 8
    for (int i = 0; i < 64; ++i) a = fmaf(hn[r][i], W1s[i * 64 + o], a);
    t1[r][o] = fmaxf(a, 0.f);
    __syncthreads();
    float a2 = b2s[o];
    #pragma unroll 8
    for (int i = 0; i < 64; ++i) a2 = fmaf(t1[r][i], W2s[i * 64 + o], a2);
    out[row * 64 + o] = a2;
    __syncthreads();
  }
}

extern "C" void kernel_launch(void* const* d_in, const int* in_sizes, int n_in,
                              void* d_out, int out_size, void* d_ws, size_t ws_size,
                              hipStream_t stream) {
  const float* x   = (const float*)d_in[0];
  const float* pos = (const float*)d_in[1];
  const int*   ei  = (const int*)d_in[2];
  const float* W1  = (const float*)d_in[6];
  const float* b1  = (const float*)d_in[7];
  const float* W2  = (const float*)d_in[8];
  const float* b2  = (const float*)d_in[9];
  const float* We1 = (const float*)d_in[10];
  const float* be1 = (const float*)d_in[11];
  const float* We2 = (const float*)d_in[12];
  const float* be2 = (const float*)d_in[13];
  const float* Wd0 = (const float*)d_in[14];
  const float* bd0 = (const float*)d_in[15];
  const float* Wd1 = (const float*)d_in[16];
  const float* bd1 = (const float*)d_in[17];
  const float* gam = (const float*)d_in[18];
  const float* bet = (const float*)d_in[19];
  const float* Wo1 = (const float*)d_in[20];
  const float* bo1 = (const float*)d_in[21];
  const float* Wo2 = (const float*)d_in[22];
  const float* bo2 = (const float*)d_in[23];

  const int* srcp = ei;
  const int* dstp = ei + NE;

  float* fv   = (float*)d_ws;                  // NV*8
  float* fe   = fv + (size_t)NV * 8;           // NE*8
  float* hb   = fe + (size_t)NE * 8;           // NG*64
  float* mu   = hb + NG * 64;                  // 64
  float* rstd = mu + 64;                       // 64

  hipLaunchKernelGGL(k_vertex_mlp, dim3(NV / BE), dim3(256), 0, stream,
                     x, W1, b1, W2, b2, fv);
  hipLaunchKernelGGL(k_edge_mlp, dim3(NE / BE), dim3(256), 0, stream,
                     x, pos, srcp, dstp, We1, be1, We2, be2, fe);
  hipLaunchKernelGGL(k_graph_reduce, dim3(NG), dim3(256), 0, stream,
                     fv, fe, srcp, dstp, Wd0, bd0, Wd1, bd1, hb);
  hipLaunchKernelGGL(k_bn_stats, dim3(1), dim3(256), 0, stream, hb, mu, rstd);
  hipLaunchKernelGGL(k_out_mlp, dim3(NG / 16), dim3(256), 0, stream,
                     hb, mu, rstd, gam, bet, Wo1, bo1, Wo2, bo2, (float*)d_out);
}

// Round 6
// 370.304 us; speedup vs baseline: 7.2440x; 1.0888x over previous
//
#include <hip/hip_runtime.h>
#include <math.h>

#define NV 204800
#define NE 409600
#define NG 512
#define V_PER 400
#define E_PER 800

#define BM 128   // rows per block in the projection GEMM
#define KT 32    // k-tile

// Wt column swizzle: word j -> j ^ (((j>>5)&1)<<2). Makes the 16-address
// stride-32B w-reads hit all 8 bank-quads 2-way (free) instead of 4-way.
__device__ __forceinline__ int wswz(int j) { return j ^ (((j >> 5) & 1) << 2); }

// ---- Kernel 1: fused projection GEMM  y = x @ [W1 | We1[0:128]]  ----------
// Epilogue: cols 0-63 -> relu(+b1) -> layer2 -> sigmoid -> fv  (vertex MLP)
//           cols 64-127 -> raw y2 (edge projection, consumed by k_edge_finish)
__global__ __launch_bounds__(256)
void k_proj(const float* __restrict__ x, const float* __restrict__ W1,
            const float* __restrict__ b1, const float* __restrict__ W2,
            const float* __restrict__ b2, const float* __restrict__ We1,
            float* __restrict__ fv, float* __restrict__ y2) {
  // union: phase1 = xt[32][128] (16KB) + Wt[32][128] (16KB); phase2 = hs[128][65]
  __shared__ __align__(16) char smem[33280];
  float (*xt)[BM] = (float (*)[BM])smem;
  float (*Wt)[BM] = (float (*)[BM])(smem + KT * BM * 4);
  float (*hs)[65] = (float (*)[65])smem;
  __shared__ float W2s[64 * 8];

  const int tid = threadIdx.x;
  const long vb = (long)blockIdx.x * BM;

  if (tid < 128) ((float4*)W2s)[tid] = ((const float4*)W2)[tid];

  const int v = tid >> 1, h = tid & 1;      // staging: 2 threads per row
  const int jg = tid & 15, rg = tid >> 4;   // compute: 16 col-grps x 16 row-grps

  // swizzled w-read word bases (hoisted; constant per thread)
  const int wb0 = wswz(jg * 8);
  const int wb1 = wswz(jg * 8 + 4);

  float acc[8][8];
  #pragma unroll
  for (int i = 0; i < 8; ++i)
    #pragma unroll
    for (int j = 0; j < 8; ++j) acc[i][j] = 0.f;

  #pragma unroll 1
  for (int t = 0; t < 4; ++t) {
    { // stage x tile (transposed) and both weight halves (swizzled cols)
      const float4* src = (const float4*)(x + (vb + v) * 128 + t * KT + h * 16);
      const float4 a0 = src[0], a1 = src[1], a2 = src[2], a3 = src[3];
      const int r = h * 16;
      xt[r + 0][v] = a0.x; xt[r + 1][v] = a0.y; xt[r + 2][v] = a0.z; xt[r + 3][v] = a0.w;
      xt[r + 4][v] = a1.x; xt[r + 5][v] = a1.y; xt[r + 6][v] = a1.z; xt[r + 7][v] = a1.w;
      xt[r + 8][v] = a2.x; xt[r + 9][v] = a2.y; xt[r +10][v] = a2.z; xt[r +11][v] = a2.w;
      xt[r +12][v] = a3.x; xt[r +13][v] = a3.y; xt[r +14][v] = a3.z; xt[r +15][v] = a3.w;
      #pragma unroll
      for (int q = 0; q < 2; ++q) {
        const int idx = tid + q * 256;          // 512 float4 per slab
        const int kk = idx >> 4, j4 = idx & 15;
        const float4 wa = ((const float4*)(W1 + t * KT * 64))[idx];
        const float4 wb = ((const float4*)(We1 + t * KT * 64))[idx];
        *(float4*)&Wt[kk][wswz(j4 * 4)] = wa;
        *(float4*)&Wt[kk][wswz(64 + j4 * 4)] = wb;
      }
    }
    __syncthreads();
    #pragma unroll
    for (int kk = 0; kk < KT; ++kk) {
      const float4 av0 = *(const float4*)&xt[kk][rg * 8];
      const float4 av1 = *(const float4*)&xt[kk][rg * 8 + 4];
      const float4 w0 = *(const float4*)&Wt[kk][wb0];
      const float4 w1 = *(const float4*)&Wt[kk][wb1];
      const float a[8] = {av0.x, av0.y, av0.z, av0.w, av1.x, av1.y, av1.z, av1.w};
      const float w[8] = {w0.x, w0.y, w0.z, w0.w, w1.x, w1.y, w1.z, w1.w};
      #pragma unroll
      for (int i = 0; i < 8; ++i)
        #pragma unroll
        for (int j = 0; j < 8; ++j) acc[i][j] = fmaf(a[i], w[j], acc[i][j]);
    }
    __syncthreads();
  }

  // epilogue: y1 -> hs (relu + b1), y2 -> global raw
  if (jg < 8) {
    const float4 b1a = *(const float4*)(b1 + jg * 8);
    const float4 b1b = *(const float4*)(b1 + jg * 8 + 4);
    #pragma unroll
    for (int i = 0; i < 8; ++i) {
      const int row = rg * 8 + i;
      *(float4*)&hs[row][jg * 8] = make_float4(
          fmaxf(acc[i][0] + b1a.x, 0.f), fmaxf(acc[i][1] + b1a.y, 0.f),
          fmaxf(acc[i][2] + b1a.z, 0.f), fmaxf(acc[i][3] + b1a.w, 0.f));
      *(float4*)&hs[row][jg * 8 + 4] = make_float4(
          fmaxf(acc[i][4] + b1b.x, 0.f), fmaxf(acc[i][5] + b1b.y, 0.f),
          fmaxf(acc[i][6] + b1b.z, 0.f), fmaxf(acc[i][7] + b1b.w, 0.f));
    }
  } else {
    #pragma unroll
    for (int i = 0; i < 8; ++i) {
      const long row = vb + rg * 8 + i;
      *(float4*)&y2[row * 64 + (jg - 8) * 8] =
          make_float4(acc[i][0], acc[i][1], acc[i][2], acc[i][3]);
      *(float4*)&y2[row * 64 + (jg - 8) * 8 + 4] =
          make_float4(acc[i][4], acc[i][5], acc[i][6], acc[i][7]);
    }
  }
  __syncthreads();

  // vertex layer 2 + sigmoid (R3-proven pattern)
  const int jg2 = tid & 7, eg2 = tid >> 3;
  float p[4][8];
  #pragma unroll
  for (int i = 0; i < 4; ++i)
    #pragma unroll
    for (int o = 0; o < 8; ++o) p[i][o] = 0.f;
  #pragma unroll
  for (int jj = 0; jj < 8; ++jj) {
    const float4 w20 = *(const float4*)&W2s[(jg2 * 8 + jj) * 8];
    const float4 w21 = *(const float4*)&W2s[(jg2 * 8 + jj) * 8 + 4];
    const float w2r[8] = {w20.x, w20.y, w20.z, w20.w, w21.x, w21.y, w21.z, w21.w};
    #pragma unroll
    for (int i = 0; i < 4; ++i) {
      const float hv = hs[eg2 * 4 + i][jg2 * 8 + jj];
      #pragma unroll
      for (int o = 0; o < 8; ++o) p[i][o] = fmaf(hv, w2r[o], p[i][o]);
    }
  }
  #pragma unroll
  for (int m = 1; m <= 4; m <<= 1)
    #pragma unroll
    for (int i = 0; i < 4; ++i)
      #pragma unroll
      for (int o = 0; o < 8; ++o) p[i][o] += __shfl_xor(p[i][o], m, 64);

  if (jg2 < 4) {
    const float4 b2a = *(const float4*)b2;
    const float4 b2b = *(const float4*)(b2 + 4);
    const float b2r[8] = {b2a.x, b2a.y, b2a.z, b2a.w, b2b.x, b2b.y, b2b.z, b2b.w};
    const long row = vb + eg2 * 4 + jg2;
    float vout[8];
    #pragma unroll
    for (int o = 0; o < 8; ++o) vout[o] = 1.0f / (1.0f + __expf(-(p[jg2][o] + b2r[o])));
    *(float4*)&fv[row * 8]     = make_float4(vout[0], vout[1], vout[2], vout[3]);
    *(float4*)&fv[row * 8 + 4] = make_float4(vout[4], vout[5], vout[6], vout[7]);
  }
}

// ---- Kernel 2: edge finish  fe = sigmoid(relu(y2[s]+y2[d]+dist*wd+be1)@We2+be2)
// 8 threads per edge (jg = tid&7 owns hidden dims jg*8..+7); We2 rows in regs.
__global__ __launch_bounds__(256)
void k_edge_finish(const float* __restrict__ y2, const float* __restrict__ pos,
                   const int* __restrict__ srcp, const int* __restrict__ dstp,
                   const float* __restrict__ We1, const float* __restrict__ be1,
                   const float* __restrict__ We2, const float* __restrict__ be2,
                   float* __restrict__ fe) {
  const int tid = threadIdx.x;
  const int jg = tid & 7;
  const long ebase = (long)blockIdx.x * 256;

  // per-thread invariant params
  float w2[64];                       // We2 rows jg*8..jg*8+7 (contiguous 64 floats)
  #pragma unroll
  for (int q = 0; q < 16; ++q)
    *(float4*)&w2[q * 4] = ((const float4*)(We2 + jg * 64))[q];
  const float4 wda = *(const float4*)(We1 + 128 * 64 + jg * 8);
  const float4 wdb = *(const float4*)(We1 + 128 * 64 + jg * 8 + 4);
  const float4 bea = *(const float4*)(be1 + jg * 8);
  const float4 beb = *(const float4*)(be1 + jg * 8 + 4);
  const float wd[8] = {wda.x, wda.y, wda.z, wda.w, wdb.x, wdb.y, wdb.z, wdb.w};
  const float be[8] = {bea.x, bea.y, bea.z, bea.w, beb.x, beb.y, beb.z, beb.w};
  const float4 b2a = *(const float4*)be2;
  const float4 b2b = *(const float4*)(be2 + 4);

  #pragma unroll 1
  for (int ps = 0; ps < 8; ++ps) {
    const long e = ebase + ps * 32 + (tid >> 3);
    const int s = srcp[e], d = dstp[e];
    const float4 a0 = *(const float4*)(y2 + (long)s * 64 + jg * 8);
    const float4 a1 = *(const float4*)(y2 + (long)s * 64 + jg * 8 + 4);
    const float4 c0 = *(const float4*)(y2 + (long)d * 64 + jg * 8);
    const float4 c1 = *(const float4*)(y2 + (long)d * 64 + jg * 8 + 4);
    const float dx = pos[s * 3 + 0] - pos[d * 3 + 0];
    const float dy = pos[s * 3 + 1] - pos[d * 3 + 1];
    const float dz = pos[s * 3 + 2] - pos[d * 3 + 2];
    const float dist = sqrtf(dx * dx + dy * dy + dz * dz);
    float hh[8] = {a0.x + c0.x, a0.y + c0.y, a0.z + c0.z, a0.w + c0.w,
                   a1.x + c1.x, a1.y + c1.y, a1.z + c1.z, a1.w + c1.w};
    float p[8];
    #pragma unroll
    for (int o = 0; o < 8; ++o) p[o] = 0.f;
    #pragma unroll
    for (int jj = 0; jj < 8; ++jj) {
      const float hv = fmaxf(fmaf(dist, wd[jj], hh[jj] + be[jj]), 0.f);
      #pragma unroll
      for (int o = 0; o < 8; ++o) p[o] = fmaf(hv, w2[jj * 8 + o], p[o]);
    }
    #pragma unroll
    for (int m = 1; m <= 4; m <<= 1)
      #pragma unroll
      for (int o = 0; o < 8; ++o) p[o] += __shfl_xor(p[o], m, 64);
    if (jg == 0) {
      float vout[8];
      const float b2r[8] = {b2a.x, b2a.y, b2a.z, b2a.w, b2b.x, b2b.y, b2b.z, b2b.w};
      #pragma unroll
      for (int o = 0; o < 8; ++o) vout[o] = 1.0f / (1.0f + __expf(-(p[o] + b2r[o])));
      *(float4*)&fe[e * 8]     = make_float4(vout[0], vout[1], vout[2], vout[3]);
      *(float4*)&fe[e * 8 + 4] = make_float4(vout[4], vout[5], vout[6], vout[7]);
    }
  }
}

// ------- Kernel 3: per-graph LDS scatter min/max + reduce + lin0 -> h -------
__global__ __launch_bounds__(256, 2)
void k_graph_reduce(const float* __restrict__ fv, const float* __restrict__ fe,
                    const int* __restrict__ srcp, const int* __restrict__ dstp,
                    const float* __restrict__ Wd0, const float* __restrict__ bd0,
                    const float* __restrict__ Wd1, const float* __restrict__ bd1,
                    float* __restrict__ hbuf) {
  __shared__ unsigned dminS[8 * V_PER];
  __shared__ unsigned dmaxS[8 * V_PER];
  __shared__ float red[256];
  __shared__ float sums[3][8];
  const int tid = threadIdx.x;
  const int g = blockIdx.x;

  for (int i = tid; i < 8 * V_PER; i += 256) {
    dminS[i] = 0x7F800000u;  // +inf (fe > 0 so uint compare == float compare)
    dmaxS[i] = 0u;
  }
  __syncthreads();

  const int eb = g * E_PER;
  const int vb = g * V_PER;
  for (int e = tid; e < E_PER; e += 256) {
    const int ls = srcp[eb + e] - vb;
    const int ld = dstp[eb + e] - vb;
    const uint4 f0 = ((const uint4*)(fe + (long)(eb + e) * 8))[0];
    const uint4 f1 = ((const uint4*)(fe + (long)(eb + e) * 8))[1];
    const unsigned fb[8] = {f0.x, f0.y, f0.z, f0.w, f1.x, f1.y, f1.z, f1.w};
    #pragma unroll
    for (int f = 0; f < 8; ++f) {
      atomicMin(&dminS[f * V_PER + ls], fb[f]);
      atomicMax(&dmaxS[f * V_PER + ls], fb[f]);
      atomicMin(&dminS[f * V_PER + ld], fb[f]);
      atomicMax(&dmaxS[f * V_PER + ld], fb[f]);
    }
  }
  __syncthreads();

  const int f = tid & 7;
  float sfv = 0.f, smin = 0.f, smax = 0.f;
  for (int v = tid >> 3; v < V_PER; v += 32) {
    sfv += fv[(long)(vb + v) * 8 + f];
    const unsigned mn = dminS[f * V_PER + v];
    if (mn == 0x7F800000u) { smin += 1.0f; smax += 1.0f; }
    else { smin += __uint_as_float(mn); smax += __uint_as_float(dmaxS[f * V_PER + v]); }
  }
  red[tid] = sfv; __syncthreads();
  for (int s = 128; s >= 8; s >>= 1) { if (tid < s) red[tid] += red[tid + s]; __syncthreads(); }
  if (tid < 8) sums[0][tid] = red[tid];
  __syncthreads();
  red[tid] = smax; __syncthreads();
  for (int s = 128; s >= 8; s >>= 1) { if (tid < s) red[tid] += red[tid + s]; __syncthreads(); }
  if (tid < 8) sums[1][tid] = red[tid];
  __syncthreads();
  red[tid] = smin; __syncthreads();
  for (int s = 128; s >= 8; s >>= 1) { if (tid < s) red[tid] += red[tid + s]; __syncthreads(); }
  if (tid < 8) sums[2][tid] = red[tid];
  __syncthreads();

  if (tid < 64) {
    const int o = tid;
    const float inv = 1.0f / (float)V_PER;
    float acc = bd0[o];
    #pragma unroll
    for (int ff = 0; ff < 8; ++ff) {
      acc = fmaf(sums[0][ff] * inv, Wd0[(4 * ff + 1) * 64 + o], acc);
      acc = fmaf(sums[1][ff] * inv, Wd0[(4 * ff + 2) * 64 + o], acc);
      acc = fmaf(sums[2][ff] * inv, Wd0[(4 * ff + 3) * 64 + o], acc);
    }
    const float x1 = Wd1[64 + o] + Wd1[128 + o] + Wd1[192 + o] + bd1[o];
    hbuf[g * 64 + o] = acc + x1;
  }
}

// ---------------- Kernel 4: BatchNorm stats over 512 graphs -----------------
__global__ __launch_bounds__(256)
void k_bn_stats(const float* __restrict__ hbuf, float* __restrict__ mu,
                float* __restrict__ rstd) {
  __shared__ float rs[256], rs2[256];
  const int tid = threadIdx.x;
  const int c = tid & 63, rg = tid >> 6;
  float s = 0.f, s2 = 0.f;
  for (int r = rg * 128; r < rg * 128 + 128; ++r) {
    const float v = hbuf[r * 64 + c];
    s += v; s2 += v * v;
  }
  rs[tid] = s; rs2[tid] = s2; __syncthreads();
  if (tid < 128) { rs[tid] += rs[tid + 128]; rs2[tid] += rs2[tid + 128]; }
  __syncthreads();
  if (tid < 64) {
    const float st = rs[tid] + rs[tid + 64];
    const float st2 = rs2[tid] + rs2[tid + 64];
    const float m = st / 512.0f;
    const float var = st2 / 512.0f - m * m;
    mu[tid] = m;
    rstd[tid] = rsqrtf(var + 1e-5f);
  }
}

// ---------------- Kernel 5: BN apply + out MLP ------------------------------
__global__ __launch_bounds__(256)
void k_out_mlp(const float* __restrict__ hbuf, const float* __restrict__ mu,
               const float* __restrict__ rstd, const float* __restrict__ gam,
               const float* __restrict__ bet, const float* __restrict__ Wo1,
               const float* __restrict__ bo1, const float* __restrict__ Wo2,
               const float* __restrict__ bo2, float* __restrict__ out) {
  __shared__ float W1s[64 * 64], W2s[64 * 64];
  __shared__ float hn[4][64], t1[4][64];
  __shared__ float mus[64], rstds[64], gs[64], bs[64], b1s[64], b2s[64];
  const int tid = threadIdx.x;
  for (int i = tid; i < 4096; i += 256) { W1s[i] = Wo1[i]; W2s[i] = Wo2[i]; }
  if (tid < 64) {
    mus[tid] = mu[tid]; rstds[tid] = rstd[tid]; gs[tid] = gam[tid];
    bs[tid] = bet[tid]; b1s[tid] = bo1[tid]; b2s[tid] = bo2[tid];
  }
  __syncthreads();
  const int r = tid >> 6, o = tid & 63;
  for (int it = 0; it < 4; ++it) {
    const int row = blockIdx.x * 16 + it * 4 + r;
    hn[r][o] = (hbuf[row * 64 + o] - mus[o]) * rstds[o] * gs[o] + bs[o];
    __syncthreads();
    float a = b1s[o];
    #pragma unroll 8
    for (int i = 0; i < 64; ++i) a = fmaf(hn[r][i], W1s[i * 64 + o], a);
    t1[r][o] = fmaxf(a, 0.f);
    __syncthreads();
    float a2 = b2s[o];
    #pragma unroll 8
    for (int i = 0; i < 64; ++i) a2 = fmaf(t1[r][i], W2s[i * 64 + o], a2);
    out[row * 64 + o] = a2;
    __syncthreads();
  }
}

extern "C" void kernel_launch(void* const* d_in, const int* in_sizes, int n_in,
                              void* d_out, int out_size, void* d_ws, size_t ws_size,
                              hipStream_t stream) {
  const float* x   = (const float*)d_in[0];
  const float* pos = (const float*)d_in[1];
  const int*   ei  = (const int*)d_in[2];
  const float* W1  = (const float*)d_in[6];
  const float* b1  = (const float*)d_in[7];
  const float* W2  = (const float*)d_in[8];
  const float* b2  = (const float*)d_in[9];
  const float* We1 = (const float*)d_in[10];
  const float* be1 = (const float*)d_in[11];
  const float* We2 = (const float*)d_in[12];
  const float* be2 = (const float*)d_in[13];
  const float* Wd0 = (const float*)d_in[14];
  const float* bd0 = (const float*)d_in[15];
  const float* Wd1 = (const float*)d_in[16];
  const float* bd1 = (const float*)d_in[17];
  const float* gam = (const float*)d_in[18];
  const float* bet = (const float*)d_in[19];
  const float* Wo1 = (const float*)d_in[20];
  const float* bo1 = (const float*)d_in[21];
  const float* Wo2 = (const float*)d_in[22];
  const float* bo2 = (const float*)d_in[23];

  const int* srcp = ei;
  const int* dstp = ei + NE;

  float* fv   = (float*)d_ws;                  // NV*8      = 1.64M floats
  float* fe   = fv + (size_t)NV * 8;           // NE*8      = 3.28M floats
  float* hb   = fe + (size_t)NE * 8;           // NG*64
  float* mu   = hb + NG * 64;                  // 64
  float* rstd = mu + 64;                       // 64
  float* y2   = rstd + 64;                     // NV*64     = 13.1M floats (52.4 MB)

  hipLaunchKernelGGL(k_proj, dim3(NV / BM), dim3(256), 0, stream,
                     x, W1, b1, W2, b2, We1, fv, y2);
  hipLaunchKernelGGL(k_edge_finish, dim3(NE / 256), dim3(256), 0, stream,
                     y2, pos, srcp, dstp, We1, be1, We2, be2, fe);
  hipLaunchKernelGGL(k_graph_reduce, dim3(NG), dim3(256), 0, stream,
                     fv, fe, srcp, dstp, Wd0, bd0, Wd1, bd1, hb);
  hipLaunchKernelGGL(k_bn_stats, dim3(1), dim3(256), 0, stream, hb, mu, rstd);
  hipLaunchKernelGGL(k_out_mlp, dim3(NG / 16), dim3(256), 0, stream,
                     hb, mu, rstd, gam, bet, Wo1, bo1, Wo2, bo2, (float*)d_out);
}